// Round 2
// baseline (6023.248 us; speedup 1.0000x reference)
//
#include <hip/hip_runtime.h>

#define Nn 256
#define Tt 128
#define Dd 512
#define Hh 1024
#define G4 4096     // 4*H
#define KK 2560     // full W cols: x(512) | h(1024) | attn(1024)
#define KSTEP 1536  // per-step GEMM K: x + h only
#define KHALF 768
#define NIT 12      // KHALF / 64

typedef __attribute__((ext_vector_type(8))) short s8v;
typedef __attribute__((ext_vector_type(4))) short s4v;
typedef __attribute__((ext_vector_type(4))) float f4v;

__device__ __forceinline__ float bf2f(ushort u) {
    union { unsigned int i; float f; } v; v.i = ((unsigned int)u) << 16; return v.f;
}
__device__ __forceinline__ ushort f2bf(float f) {   // round-to-nearest-even
    union { float f; unsigned int i; } v; v.f = f;
    unsigned int x = v.i;
    return (ushort)((x + 0x7fffu + ((x >> 16) & 1u)) >> 16);
}
__device__ __forceinline__ void split2(float f, ushort& hi, ushort& lo) {
    hi = f2bf(f);
    lo = f2bf(f - bf2f(hi));
}

// ---------------------------------------------------------------------------
// One-time: W = [Wx; Wh; Wattn] (2560 x 4096 fp32) -> Whi/Wlo[j][k] bf16
// ---------------------------------------------------------------------------
__global__ __launch_bounds__(256) void prep_W(
    const float* __restrict__ Wx, const float* __restrict__ Wh,
    const float* __restrict__ Wa, ushort* __restrict__ Whi,
    ushort* __restrict__ Wlo)
{
    __shared__ float tile[64 * 65];
    int kb = blockIdx.x * 64;
    int jb = blockIdx.y * 64;
    const float* src; int kofs;
    if (kb < Dd)            { src = Wx; kofs = kb; }
    else if (kb < Dd + Hh)  { src = Wh; kofs = kb - Dd; }
    else                    { src = Wa; kofs = kb - Dd - Hh; }
    int tid = threadIdx.x;
    int r = tid >> 2;            // 0..63
    int c16 = (tid & 3) * 16;    // 0,16,32,48
    const float* sp = src + (size_t)(kofs + r) * G4 + jb + c16;
    #pragma unroll
    for (int i = 0; i < 16; i++) tile[(c16 + i) * 65 + r] = sp[i];
    __syncthreads();
    ushort hi[16], lo[16];
    #pragma unroll
    for (int i = 0; i < 16; i++) split2(tile[r * 65 + c16 + i], hi[i], lo[i]);
    size_t o = (size_t)(jb + r) * KK + kb + c16;
    #pragma unroll
    for (int p = 0; p < 2; p++) {
        s8v vh, vl;
        #pragma unroll
        for (int i = 0; i < 8; i++) { vh[i] = (short)hi[p * 8 + i]; vl[i] = (short)lo[p * 8 + i]; }
        *(s8v*)&Whi[o + p * 8] = vh;
        *(s8v*)&Wlo[o + p * 8] = vl;
    }
}

// ---------------------------------------------------------------------------
// One-time: transpose+split A (N,H,16) -> At[(n*16+l)][h] bf16 hi/lo
// ---------------------------------------------------------------------------
__global__ __launch_bounds__(256) void prep_A(
    const float* __restrict__ A, ushort* __restrict__ Athi,
    ushort* __restrict__ Atlo)
{
    int n = blockIdx.x;
    int tid = threadIdx.x;
    int h0 = tid * 4;
    float v[4][16];
    #pragma unroll
    for (int r = 0; r < 4; r++) {
        const f4v* p = (const f4v*)(A + ((size_t)n * Hh + h0 + r) * 16);
        #pragma unroll
        for (int q = 0; q < 4; q++) {
            f4v xv = p[q];
            v[r][q * 4 + 0] = xv[0]; v[r][q * 4 + 1] = xv[1];
            v[r][q * 4 + 2] = xv[2]; v[r][q * 4 + 3] = xv[3];
        }
    }
    #pragma unroll
    for (int l = 0; l < 16; l++) {
        s4v vh, vl;
        #pragma unroll
        for (int r = 0; r < 4; r++) {
            ushort hi, lo; split2(v[r][l], hi, lo);
            vh[r] = (short)hi; vl[r] = (short)lo;
        }
        size_t o = ((size_t)n * 16 + l) * Hh + h0;
        *(s4v*)&Athi[o] = vh;
        *(s4v*)&Atlo[o] = vl;
    }
}

// ---------------------------------------------------------------------------
// One-time: AW[(n*16+l)][j] = sum_h A[n,h,l] * Wattn[h,j]   (fp32 out)
// ---------------------------------------------------------------------------
__global__ __launch_bounds__(256) void aw_gemm(
    const ushort* __restrict__ Athi, const ushort* __restrict__ Atlo,
    const ushort* __restrict__ Whi, const ushort* __restrict__ Wlo,
    float* __restrict__ AW)
{
    __shared__ ushort Ahi[64 * 72], Alo[64 * 72];
    __shared__ ushort Bhi[64 * 72], Blo[64 * 72];
    int j0 = blockIdx.x * 64;
    int m0 = blockIdx.y * 64;
    int tid = threadIdx.x;
    int lane = tid & 63, wave = tid >> 6;
    int l15 = lane & 15, quad = lane >> 4;
    f4v acc[4];
    #pragma unroll
    for (int s = 0; s < 4; s++) acc[s] = (f4v){0.f, 0.f, 0.f, 0.f};
    int rs = tid >> 3;
    int cs = (tid & 7) * 8;
    for (int kb = 0; kb < Hh; kb += 64) {
        __syncthreads();
        #pragma unroll
        for (int p = 0; p < 2; p++) {
            int r = rs + 32 * p;
            size_t oa = (size_t)(m0 + r) * Hh + kb + cs;
            *(s8v*)&Ahi[r * 72 + cs] = *(const s8v*)&Athi[oa];
            *(s8v*)&Alo[r * 72 + cs] = *(const s8v*)&Atlo[oa];
            size_t ob = (size_t)(j0 + r) * KK + (Dd + Hh) + kb + cs;
            *(s8v*)&Bhi[r * 72 + cs] = *(const s8v*)&Whi[ob];
            *(s8v*)&Blo[r * 72 + cs] = *(const s8v*)&Wlo[ob];
        }
        __syncthreads();
        #pragma unroll
        for (int ks = 0; ks < 2; ks++) {
            s8v ah = *(const s8v*)&Ahi[(wave * 16 + l15) * 72 + ks * 32 + quad * 8];
            s8v al = *(const s8v*)&Alo[(wave * 16 + l15) * 72 + ks * 32 + quad * 8];
            #pragma unroll
            for (int s = 0; s < 4; s++) {
                s8v bh = *(const s8v*)&Bhi[(s * 16 + l15) * 72 + ks * 32 + quad * 8];
                s8v bl = *(const s8v*)&Blo[(s * 16 + l15) * 72 + ks * 32 + quad * 8];
                acc[s] = __builtin_amdgcn_mfma_f32_16x16x32_bf16(ah, bh, acc[s], 0, 0, 0);
                acc[s] = __builtin_amdgcn_mfma_f32_16x16x32_bf16(ah, bl, acc[s], 0, 0, 0);
                acc[s] = __builtin_amdgcn_mfma_f32_16x16x32_bf16(al, bh, acc[s], 0, 0, 0);
            }
        }
    }
    #pragma unroll
    for (int s = 0; s < 4; s++) {
        int j = j0 + s * 16 + l15;
        #pragma unroll
        for (int rr = 0; rr < 4; rr++) {
            int row = m0 + wave * 16 + quad * 4 + rr;
            AW[(size_t)row * G4 + j] = acc[s][rr];
        }
    }
}

// ---------------------------------------------------------------------------
// One-time: h0 = c0 = mean_l A[n][h][l];  also h0 split hi/lo
// ---------------------------------------------------------------------------
__global__ __launch_bounds__(256) void init_h0(
    const float* __restrict__ A, float* __restrict__ h, float* __restrict__ c,
    ushort* __restrict__ hhi, ushort* __restrict__ hlo)
{
    int i = blockIdx.x * 256 + threadIdx.x;   // < N*H
    const float* ap = A + (size_t)i * 16;
    float s = 0.f;
    #pragma unroll
    for (int l = 0; l < 16; l++) s += ap[l];
    s *= (1.f / 16.f);
    h[i] = s; c[i] = s;
    ushort hi, lo; split2(s, hi, lo);
    hhi[i] = hi; hlo[i] = lo;
}

// ---------------------------------------------------------------------------
// One-time: softmax weights from h0 (per n). Loop steps get w from lstm_fused.
// ---------------------------------------------------------------------------
__global__ __launch_bounds__(256) void calc_w(
    const float* __restrict__ A, const float* __restrict__ h,
    float* __restrict__ wbuf)
{
    int n = blockIdx.x;
    int tid = threadIdx.x;
    int lane = tid & 63, wave = tid >> 6;
    __shared__ float red[4][16];
    float part[16];
    #pragma unroll
    for (int l = 0; l < 16; l++) part[l] = 0.f;
    #pragma unroll
    for (int rr = 0; rr < 4; rr++) {
        int hh = tid + rr * 256;
        float hv = h[n * Hh + hh];
        const f4v* ap = (const f4v*)(A + ((size_t)n * Hh + hh) * 16);
        #pragma unroll
        for (int q = 0; q < 4; q++) {
            f4v v = ap[q];
            part[q * 4 + 0] += v[0] * hv; part[q * 4 + 1] += v[1] * hv;
            part[q * 4 + 2] += v[2] * hv; part[q * 4 + 3] += v[3] * hv;
        }
    }
    #pragma unroll
    for (int l = 0; l < 16; l++) {
        float v = part[l];
        #pragma unroll
        for (int off = 32; off > 0; off >>= 1) v += __shfl_down(v, off);
        if (lane == 0) red[wave][l] = v;
    }
    __syncthreads();
    if (tid == 0) {
        float sc[16]; float mx = -3.4e38f;
        #pragma unroll
        for (int l = 0; l < 16; l++) {
            sc[l] = (red[0][l] + red[1][l] + red[2][l] + red[3][l]) * 0.03125f;
            mx = fmaxf(mx, sc[l]);
        }
        float sum = 0.f;
        #pragma unroll
        for (int l = 0; l < 16; l++) { sc[l] = expf(sc[l] - mx); sum += sc[l]; }
        float inv = 1.f / sum;
        #pragma unroll
        for (int l = 0; l < 16; l++) wbuf[n * 16 + l] = sc[l] * inv;
    }
}

// ---------------------------------------------------------------------------
// Per step: K-split halves (blockIdx.z), 128n x 64j tile, double-buffered LDS.
// Each wave: 32n x 64j (2x4 16x16 tiles). One barrier per k-iter.
// ---------------------------------------------------------------------------
__global__ __launch_bounds__(256, 1) void gemm_step(
    const float* __restrict__ x,
    const ushort* __restrict__ hhi, const ushort* __restrict__ hlo,
    const ushort* __restrict__ Whi, const ushort* __restrict__ Wlo,
    float* __restrict__ g0, float* __restrict__ g1, int t)
{
    __shared__ ushort Ah[2][128 * 72], Al[2][128 * 72];
    __shared__ ushort Bh[2][64 * 72],  Bl[2][64 * 72];
    const int j0 = blockIdx.x * 64;
    const int n0 = blockIdx.y * 128;
    const int kb0 = blockIdx.z * KHALF;
    float* gout = blockIdx.z ? g1 : g0;
    const int tid = threadIdx.x;
    const int lane = tid & 63, wave = tid >> 6;
    const int l15 = lane & 15, quad = lane >> 4;
    const int rs = tid >> 3, cs = (tid & 7) * 8;

    f4v acc[2][4];
    #pragma unroll
    for (int rt = 0; rt < 2; rt++)
        #pragma unroll
        for (int ct = 0; ct < 4; ct++) acc[rt][ct] = (f4v){0.f, 0.f, 0.f, 0.f};

    // staging registers (tile in flight)
    f4v xr[4][2];
    s8v arh[4], arl[4];
    s8v brh[2], brl[2];
    int ldx = 0;

    auto LOADT = [&](int kb) {
        ldx = (kb < Dd) ? 1 : 0;
        if (ldx) {
            #pragma unroll
            for (int p = 0; p < 4; p++) {
                const f4v* ap = (const f4v*)(x + ((size_t)(n0 + rs + 32 * p) * Tt + t) * Dd + kb + cs);
                xr[p][0] = ap[0]; xr[p][1] = ap[1];
            }
        } else {
            int ko = kb - Dd;
            #pragma unroll
            for (int p = 0; p < 4; p++) {
                size_t o = (size_t)(n0 + rs + 32 * p) * Hh + ko + cs;
                arh[p] = *(const s8v*)&hhi[o];
                arl[p] = *(const s8v*)&hlo[o];
            }
        }
        #pragma unroll
        for (int p = 0; p < 2; p++) {
            size_t o = (size_t)(j0 + rs + 32 * p) * KK + kb + cs;
            brh[p] = *(const s8v*)&Whi[o];
            brl[p] = *(const s8v*)&Wlo[o];
        }
    };
    auto WRITET = [&](int b) {
        if (ldx) {
            #pragma unroll
            for (int p = 0; p < 4; p++) {
                s8v vh, vl;
                #pragma unroll
                for (int i = 0; i < 4; i++) {
                    ushort hi_, lo_;
                    split2(xr[p][0][i], hi_, lo_);
                    vh[i] = (short)hi_; vl[i] = (short)lo_;
                    split2(xr[p][1][i], hi_, lo_);
                    vh[i + 4] = (short)hi_; vl[i + 4] = (short)lo_;
                }
                *(s8v*)&Ah[b][(rs + 32 * p) * 72 + cs] = vh;
                *(s8v*)&Al[b][(rs + 32 * p) * 72 + cs] = vl;
            }
        } else {
            #pragma unroll
            for (int p = 0; p < 4; p++) {
                *(s8v*)&Ah[b][(rs + 32 * p) * 72 + cs] = arh[p];
                *(s8v*)&Al[b][(rs + 32 * p) * 72 + cs] = arl[p];
            }
        }
        #pragma unroll
        for (int p = 0; p < 2; p++) {
            *(s8v*)&Bh[b][(rs + 32 * p) * 72 + cs] = brh[p];
            *(s8v*)&Bl[b][(rs + 32 * p) * 72 + cs] = brl[p];
        }
    };

    LOADT(kb0);
    WRITET(0);
    __syncthreads();
    int cur = 0;
    for (int it = 0; it < NIT; it++) {
        if (it + 1 < NIT) LOADT(kb0 + (it + 1) * 64);
        #pragma unroll
        for (int ks = 0; ks < 2; ks++) {
            s8v ah0 = *(const s8v*)&Ah[cur][(wave * 32 + l15) * 72 + ks * 32 + quad * 8];
            s8v ah1 = *(const s8v*)&Ah[cur][(wave * 32 + 16 + l15) * 72 + ks * 32 + quad * 8];
            s8v al0 = *(const s8v*)&Al[cur][(wave * 32 + l15) * 72 + ks * 32 + quad * 8];
            s8v al1 = *(const s8v*)&Al[cur][(wave * 32 + 16 + l15) * 72 + ks * 32 + quad * 8];
            #pragma unroll
            for (int ct = 0; ct < 4; ct++) {
                s8v bh = *(const s8v*)&Bh[cur][(ct * 16 + l15) * 72 + ks * 32 + quad * 8];
                s8v bl = *(const s8v*)&Bl[cur][(ct * 16 + l15) * 72 + ks * 32 + quad * 8];
                acc[0][ct] = __builtin_amdgcn_mfma_f32_16x16x32_bf16(ah0, bh, acc[0][ct], 0, 0, 0);
                acc[0][ct] = __builtin_amdgcn_mfma_f32_16x16x32_bf16(ah0, bl, acc[0][ct], 0, 0, 0);
                acc[0][ct] = __builtin_amdgcn_mfma_f32_16x16x32_bf16(al0, bh, acc[0][ct], 0, 0, 0);
                acc[1][ct] = __builtin_amdgcn_mfma_f32_16x16x32_bf16(ah1, bh, acc[1][ct], 0, 0, 0);
                acc[1][ct] = __builtin_amdgcn_mfma_f32_16x16x32_bf16(ah1, bl, acc[1][ct], 0, 0, 0);
                acc[1][ct] = __builtin_amdgcn_mfma_f32_16x16x32_bf16(al1, bh, acc[1][ct], 0, 0, 0);
            }
        }
        if (it + 1 < NIT) WRITET(cur ^ 1);
        __syncthreads();
        cur ^= 1;
    }
    #pragma unroll
    for (int rt = 0; rt < 2; rt++) {
        #pragma unroll
        for (int ct = 0; ct < 4; ct++) {
            int j = j0 + ct * 16 + l15;
            #pragma unroll
            for (int rr = 0; rr < 4; rr++) {
                int row = n0 + wave * 32 + rt * 16 + quad * 4 + rr;
                gout[(size_t)row * G4 + j] = acc[rt][ct][rr];
            }
        }
    }
}

// ---------------------------------------------------------------------------
// Per step: fused LSTM pointwise + attn weighted-sum (from AW) + next-step
// softmax weights. One block per n; thread handles 4 consecutive j.
// ---------------------------------------------------------------------------
__global__ __launch_bounds__(256) void lstm_fused(
    const float* __restrict__ g0, const float* __restrict__ g1,
    const float* __restrict__ bias, const float* __restrict__ AW,
    float* __restrict__ wbuf, const float* __restrict__ A,
    float* __restrict__ c, ushort* __restrict__ hhi, ushort* __restrict__ hlo,
    float* __restrict__ out, int t)
{
    int n = blockIdx.x;
    int tid = threadIdx.x;
    int lane = tid & 63, wave = tid >> 6;
    int j4 = tid * 4;
    __shared__ float wsh[16];
    __shared__ float red[4][16];
    if (tid < 16) wsh[tid] = wbuf[n * 16 + tid];
    __syncthreads();
    float w[16];
    #pragma unroll
    for (int l = 0; l < 16; l++) w[l] = wsh[l];

    f4v acc[4];
    #pragma unroll
    for (int q = 0; q < 4; q++) acc[q] = (f4v){0.f, 0.f, 0.f, 0.f};
    const float* awp = AW + (size_t)n * 16 * G4;
    #pragma unroll
    for (int l = 0; l < 16; l++) {
        float wl = w[l];
        #pragma unroll
        for (int q = 0; q < 4; q++) {
            f4v v = *(const f4v*)&awp[(size_t)l * G4 + q * Hh + j4];
            acc[q][0] += wl * v[0]; acc[q][1] += wl * v[1];
            acc[q][2] += wl * v[2]; acc[q][3] += wl * v[3];
        }
    }

    size_t base = (size_t)n * G4;
    f4v gv[4];
    #pragma unroll
    for (int q = 0; q < 4; q++) {
        f4v a0 = *(const f4v*)&g0[base + q * Hh + j4];
        f4v a1 = *(const f4v*)&g1[base + q * Hh + j4];
        f4v bv = *(const f4v*)&bias[q * Hh + j4];
        #pragma unroll
        for (int e = 0; e < 4; e++) gv[q][e] = a0[e] + a1[e] + bv[e] + acc[q][e];
    }
    int i4 = n * Hh + j4;
    f4v cold = *(const f4v*)&c[i4];
    f4v cnew, hnew;
    #pragma unroll
    for (int e = 0; e < 4; e++) {
        float si = 1.f / (1.f + expf(-gv[0][e]));
        float sf = 1.f / (1.f + expf(-gv[1][e]));
        float so = 1.f / (1.f + expf(-gv[2][e]));
        float tg = tanhf(gv[3][e]);
        float cn = sf * cold[e] + si * tg;
        float hn = so * tanhf(cn);
        cnew[e] = cn; hnew[e] = hn;
    }
    *(f4v*)&c[i4] = cnew;
    s4v vh, vl;
    #pragma unroll
    for (int e = 0; e < 4; e++) {
        ushort hi, lo; split2(hnew[e], hi, lo);
        vh[e] = (short)hi; vl[e] = (short)lo;
    }
    *(s4v*)&hhi[i4] = vh;
    *(s4v*)&hlo[i4] = vl;
    *(f4v*)&out[((size_t)n * Tt + t) * Hh + j4] = hnew;

    // next-step attention weights from hnew
    float part[16];
    #pragma unroll
    for (int l = 0; l < 16; l++) part[l] = 0.f;
    #pragma unroll
    for (int r = 0; r < 4; r++) {
        float hv = hnew[r];
        const f4v* ap = (const f4v*)(A + ((size_t)n * Hh + j4 + r) * 16);
        #pragma unroll
        for (int q = 0; q < 4; q++) {
            f4v v = ap[q];
            part[q * 4 + 0] += v[0] * hv; part[q * 4 + 1] += v[1] * hv;
            part[q * 4 + 2] += v[2] * hv; part[q * 4 + 3] += v[3] * hv;
        }
    }
    #pragma unroll
    for (int l = 0; l < 16; l++) {
        float v = part[l];
        #pragma unroll
        for (int off = 32; off > 0; off >>= 1) v += __shfl_down(v, off);
        if (lane == 0) red[wave][l] = v;
    }
    __syncthreads();
    if (tid == 0) {
        float sc[16]; float mx = -3.4e38f;
        #pragma unroll
        for (int l = 0; l < 16; l++) {
            sc[l] = (red[0][l] + red[1][l] + red[2][l] + red[3][l]) * 0.03125f;
            mx = fmaxf(mx, sc[l]);
        }
        float sum = 0.f;
        #pragma unroll
        for (int l = 0; l < 16; l++) { sc[l] = expf(sc[l] - mx); sum += sc[l]; }
        float inv = 1.f / sum;
        #pragma unroll
        for (int l = 0; l < 16; l++) wbuf[n * 16 + l] = sc[l] * inv;
    }
}

// ---------------------------------------------------------------------------
extern "C" void kernel_launch(void* const* d_in, const int* in_sizes, int n_in,
                              void* d_out, int out_size, void* d_ws, size_t ws_size,
                              hipStream_t stream)
{
    const float* x  = (const float*)d_in[0];
    const float* A  = (const float*)d_in[1];
    const float* Wx = (const float*)d_in[2];
    const float* Wh = (const float*)d_in[3];
    const float* Wa = (const float*)d_in[4];
    const float* b  = (const float*)d_in[5];
    float* out = (float*)d_out;

    // workspace layout (~137 MB)
    char* p = (char*)d_ws;
    ushort* Whi  = (ushort*)p;  p += (size_t)G4 * KK * 2;        // 20.97 MB
    ushort* Wlo  = (ushort*)p;  p += (size_t)G4 * KK * 2;        // 20.97 MB
    float*  h    = (float*)p;   p += (size_t)Nn * Hh * 4;        // 1 MB
    float*  c    = (float*)p;   p += (size_t)Nn * Hh * 4;        // 1 MB
    float*  g0   = (float*)p;   p += (size_t)Nn * G4 * 4;        // 4 MB
    float*  g1   = (float*)p;   p += (size_t)Nn * G4 * 4;        // 4 MB
    ushort* hhi  = (ushort*)p;  p += (size_t)Nn * Hh * 2;        // 0.5 MB
    ushort* hlo  = (ushort*)p;  p += (size_t)Nn * Hh * 2;        // 0.5 MB
    ushort* Athi = (ushort*)p;  p += (size_t)Nn * 16 * Hh * 2;   // 8.39 MB
    ushort* Atlo = (ushort*)p;  p += (size_t)Nn * 16 * Hh * 2;   // 8.39 MB
    float*  AW   = (float*)p;   p += (size_t)Nn * 16 * G4 * 4;   // 67.1 MB
    float*  wbuf = (float*)p;   p += (size_t)Nn * 16 * 4;        // 16 KB

    prep_W<<<dim3(KK / 64, G4 / 64), 256, 0, stream>>>(Wx, Wh, Wa, Whi, Wlo);
    prep_A<<<Nn, 256, 0, stream>>>(A, Athi, Atlo);
    aw_gemm<<<dim3(G4 / 64, (Nn * 16) / 64), 256, 0, stream>>>(
        Athi, Atlo, Whi, Wlo, AW);
    init_h0<<<(Nn * Hh) / 256, 256, 0, stream>>>(A, h, c, hhi, hlo);
    calc_w<<<Nn, 256, 0, stream>>>(A, h, wbuf);
    for (int t = 0; t < Tt; t++) {
        gemm_step<<<dim3(G4 / 64, Nn / 128, 2), 256, 0, stream>>>(
            x, hhi, hlo, Whi, Wlo, g0, g1, t);
        lstm_fused<<<Nn, 256, 0, stream>>>(
            g0, g1, b, AW, wbuf, A, c, hhi, hlo, out, t);
    }
}

// Round 3
// 5196.194 us; speedup vs baseline: 1.1592x; 1.1592x over previous
//
#include <hip/hip_runtime.h>

#define Nn 256
#define Tt 128
#define Dd 512
#define Hh 1024
#define G4 4096     // 4*H
#define KK 2560     // full W cols: x(512) | h(1024) | attn(1024)
#define KSTEP 1536  // per-step GEMM K: x + h only
#define KQ 384      // per-kz K slice
#define NIT 6       // KQ / 64

typedef __attribute__((ext_vector_type(8))) short s8v;
typedef __attribute__((ext_vector_type(4))) short s4v;
typedef __attribute__((ext_vector_type(4))) float f4v;
typedef _Float16 f16;
typedef __attribute__((ext_vector_type(4))) _Float16 h4v;

__device__ __forceinline__ float bf2f(ushort u) {
    union { unsigned int i; float f; } v; v.i = ((unsigned int)u) << 16; return v.f;
}
__device__ __forceinline__ ushort f2bf(float f) {   // round-to-nearest-even
    union { float f; unsigned int i; } v; v.f = f;
    unsigned int x = v.i;
    return (ushort)((x + 0x7fffu + ((x >> 16) & 1u)) >> 16);
}
__device__ __forceinline__ void split2(float f, ushort& hi, ushort& lo) {
    hi = f2bf(f);
    lo = f2bf(f - bf2f(hi));
}

// ---------------------------------------------------------------------------
// One-time: W = [Wx; Wh; Wattn] (2560 x 4096 fp32) -> Whi/Wlo[j][k] bf16
// ---------------------------------------------------------------------------
__global__ __launch_bounds__(256) void prep_W(
    const float* __restrict__ Wx, const float* __restrict__ Wh,
    const float* __restrict__ Wa, ushort* __restrict__ Whi,
    ushort* __restrict__ Wlo)
{
    __shared__ float tile[64 * 65];
    int kb = blockIdx.x * 64;
    int jb = blockIdx.y * 64;
    const float* src; int kofs;
    if (kb < Dd)            { src = Wx; kofs = kb; }
    else if (kb < Dd + Hh)  { src = Wh; kofs = kb - Dd; }
    else                    { src = Wa; kofs = kb - Dd - Hh; }
    int tid = threadIdx.x;
    int r = tid >> 2;            // 0..63
    int c16 = (tid & 3) * 16;    // 0,16,32,48
    const float* sp = src + (size_t)(kofs + r) * G4 + jb + c16;
    #pragma unroll
    for (int i = 0; i < 16; i++) tile[(c16 + i) * 65 + r] = sp[i];
    __syncthreads();
    ushort hi[16], lo[16];
    #pragma unroll
    for (int i = 0; i < 16; i++) split2(tile[r * 65 + c16 + i], hi[i], lo[i]);
    size_t o = (size_t)(jb + r) * KK + kb + c16;
    #pragma unroll
    for (int p = 0; p < 2; p++) {
        s8v vh, vl;
        #pragma unroll
        for (int i = 0; i < 8; i++) { vh[i] = (short)hi[p * 8 + i]; vl[i] = (short)lo[p * 8 + i]; }
        *(s8v*)&Whi[o + p * 8] = vh;
        *(s8v*)&Wlo[o + p * 8] = vl;
    }
}

// ---------------------------------------------------------------------------
// One-time: transpose+split A (N,H,16) -> At[(n*16+l)][h] bf16 hi/lo
// ---------------------------------------------------------------------------
__global__ __launch_bounds__(256) void prep_A(
    const float* __restrict__ A, ushort* __restrict__ Athi,
    ushort* __restrict__ Atlo)
{
    int n = blockIdx.x;
    int tid = threadIdx.x;
    int h0 = tid * 4;
    float v[4][16];
    #pragma unroll
    for (int r = 0; r < 4; r++) {
        const f4v* p = (const f4v*)(A + ((size_t)n * Hh + h0 + r) * 16);
        #pragma unroll
        for (int q = 0; q < 4; q++) {
            f4v xv = p[q];
            v[r][q * 4 + 0] = xv[0]; v[r][q * 4 + 1] = xv[1];
            v[r][q * 4 + 2] = xv[2]; v[r][q * 4 + 3] = xv[3];
        }
    }
    #pragma unroll
    for (int l = 0; l < 16; l++) {
        s4v vh, vl;
        #pragma unroll
        for (int r = 0; r < 4; r++) {
            ushort hi, lo; split2(v[r][l], hi, lo);
            vh[r] = (short)hi; vl[r] = (short)lo;
        }
        size_t o = ((size_t)n * 16 + l) * Hh + h0;
        *(s4v*)&Athi[o] = vh;
        *(s4v*)&Atlo[o] = vl;
    }
}

// ---------------------------------------------------------------------------
// One-time: AW[(n*16+l)][j] = sum_h A[n,h,l] * Wattn[h,j]   (fp16 out)
// ---------------------------------------------------------------------------
__global__ __launch_bounds__(256) void aw_gemm(
    const ushort* __restrict__ Athi, const ushort* __restrict__ Atlo,
    const ushort* __restrict__ Whi, const ushort* __restrict__ Wlo,
    f16* __restrict__ AW)
{
    __shared__ ushort Ahi[64 * 72], Alo[64 * 72];
    __shared__ ushort Bhi[64 * 72], Blo[64 * 72];
    int j0 = blockIdx.x * 64;
    int m0 = blockIdx.y * 64;
    int tid = threadIdx.x;
    int lane = tid & 63, wave = tid >> 6;
    int l15 = lane & 15, quad = lane >> 4;
    f4v acc[4];
    #pragma unroll
    for (int s = 0; s < 4; s++) acc[s] = (f4v){0.f, 0.f, 0.f, 0.f};
    int rs = tid >> 3;
    int cs = (tid & 7) * 8;
    for (int kb = 0; kb < Hh; kb += 64) {
        __syncthreads();
        #pragma unroll
        for (int p = 0; p < 2; p++) {
            int r = rs + 32 * p;
            size_t oa = (size_t)(m0 + r) * Hh + kb + cs;
            *(s8v*)&Ahi[r * 72 + cs] = *(const s8v*)&Athi[oa];
            *(s8v*)&Alo[r * 72 + cs] = *(const s8v*)&Atlo[oa];
            size_t ob = (size_t)(j0 + r) * KK + (Dd + Hh) + kb + cs;
            *(s8v*)&Bhi[r * 72 + cs] = *(const s8v*)&Whi[ob];
            *(s8v*)&Blo[r * 72 + cs] = *(const s8v*)&Wlo[ob];
        }
        __syncthreads();
        #pragma unroll
        for (int ks = 0; ks < 2; ks++) {
            s8v ah = *(const s8v*)&Ahi[(wave * 16 + l15) * 72 + ks * 32 + quad * 8];
            s8v al = *(const s8v*)&Alo[(wave * 16 + l15) * 72 + ks * 32 + quad * 8];
            #pragma unroll
            for (int s = 0; s < 4; s++) {
                s8v bh = *(const s8v*)&Bhi[(s * 16 + l15) * 72 + ks * 32 + quad * 8];
                s8v bl = *(const s8v*)&Blo[(s * 16 + l15) * 72 + ks * 32 + quad * 8];
                acc[s] = __builtin_amdgcn_mfma_f32_16x16x32_bf16(ah, bh, acc[s], 0, 0, 0);
                acc[s] = __builtin_amdgcn_mfma_f32_16x16x32_bf16(ah, bl, acc[s], 0, 0, 0);
                acc[s] = __builtin_amdgcn_mfma_f32_16x16x32_bf16(al, bh, acc[s], 0, 0, 0);
            }
        }
    }
    #pragma unroll
    for (int s = 0; s < 4; s++) {
        int j = j0 + s * 16 + l15;
        #pragma unroll
        for (int rr = 0; rr < 4; rr++) {
            int row = m0 + wave * 16 + quad * 4 + rr;
            AW[(size_t)row * G4 + j] = (f16)acc[s][rr];
        }
    }
}

// ---------------------------------------------------------------------------
// One-time: h0 = c0 = mean_l A[n][h][l];  also h0 split hi/lo
// ---------------------------------------------------------------------------
__global__ __launch_bounds__(256) void init_h0(
    const float* __restrict__ A, float* __restrict__ h, float* __restrict__ c,
    ushort* __restrict__ hhi, ushort* __restrict__ hlo)
{
    int i = blockIdx.x * 256 + threadIdx.x;   // < N*H
    const float* ap = A + (size_t)i * 16;
    float s = 0.f;
    #pragma unroll
    for (int l = 0; l < 16; l++) s += ap[l];
    s *= (1.f / 16.f);
    h[i] = s; c[i] = s;
    ushort hi, lo; split2(s, hi, lo);
    hhi[i] = hi; hlo[i] = lo;
}

// ---------------------------------------------------------------------------
// One-time: softmax weights from h0 (per n). Loop steps get w from lstm_fused.
// ---------------------------------------------------------------------------
__global__ __launch_bounds__(256) void calc_w(
    const float* __restrict__ A, const float* __restrict__ h,
    float* __restrict__ wbuf)
{
    int n = blockIdx.x;
    int tid = threadIdx.x;
    int lane = tid & 63, wave = tid >> 6;
    __shared__ float red[4][16];
    float part[16];
    #pragma unroll
    for (int l = 0; l < 16; l++) part[l] = 0.f;
    #pragma unroll
    for (int rr = 0; rr < 4; rr++) {
        int hh = tid + rr * 256;
        float hv = h[n * Hh + hh];
        const f4v* ap = (const f4v*)(A + ((size_t)n * Hh + hh) * 16);
        #pragma unroll
        for (int q = 0; q < 4; q++) {
            f4v v = ap[q];
            part[q * 4 + 0] += v[0] * hv; part[q * 4 + 1] += v[1] * hv;
            part[q * 4 + 2] += v[2] * hv; part[q * 4 + 3] += v[3] * hv;
        }
    }
    #pragma unroll
    for (int l = 0; l < 16; l++) {
        float v = part[l];
        #pragma unroll
        for (int off = 32; off > 0; off >>= 1) v += __shfl_down(v, off);
        if (lane == 0) red[wave][l] = v;
    }
    __syncthreads();
    if (tid == 0) {
        float sc[16]; float mx = -3.4e38f;
        #pragma unroll
        for (int l = 0; l < 16; l++) {
            sc[l] = (red[0][l] + red[1][l] + red[2][l] + red[3][l]) * 0.03125f;
            mx = fmaxf(mx, sc[l]);
        }
        float sum = 0.f;
        #pragma unroll
        for (int l = 0; l < 16; l++) { sc[l] = expf(sc[l] - mx); sum += sc[l]; }
        float inv = 1.f / sum;
        #pragma unroll
        for (int l = 0; l < 16; l++) wbuf[n * 16 + l] = sc[l] * inv;
    }
}

// ---------------------------------------------------------------------------
// Per step: K-split quarters (blockIdx.z in [0,4)), 128n x 64j tile,
// single-buffered LDS (54 KB -> 2 blocks/CU, 8 waves/CU).
// Each wave: 32n x 64j (2x4 16x16 tiles).
// ---------------------------------------------------------------------------
__global__ __launch_bounds__(256) void gemm_step(
    const float* __restrict__ x,
    const ushort* __restrict__ hhi, const ushort* __restrict__ hlo,
    const ushort* __restrict__ Whi, const ushort* __restrict__ Wlo,
    float* __restrict__ g0, float* __restrict__ g1,
    float* __restrict__ g2, float* __restrict__ g3, int t)
{
    __shared__ ushort Ah[128 * 72], Al[128 * 72];
    __shared__ ushort Bh[64 * 72],  Bl[64 * 72];
    const int j0 = blockIdx.x * 64;
    const int n0 = blockIdx.y * 128;
    const int kz = blockIdx.z;
    const int kb0 = kz * KQ;
    float* gout = (kz == 0) ? g0 : (kz == 1) ? g1 : (kz == 2) ? g2 : g3;
    const int tid = threadIdx.x;
    const int lane = tid & 63, wave = tid >> 6;
    const int l15 = lane & 15, quad = lane >> 4;
    const int rs = tid >> 3, cs = (tid & 7) * 8;

    f4v acc[2][4];
    #pragma unroll
    for (int rt = 0; rt < 2; rt++)
        #pragma unroll
        for (int ct = 0; ct < 4; ct++) acc[rt][ct] = (f4v){0.f, 0.f, 0.f, 0.f};

    for (int it = 0; it < NIT; it++) {
        int kb = kb0 + it * 64;
        __syncthreads();
        if (kb < Dd) {
            const float* xs = x + (size_t)t * Dd + kb + cs;
            #pragma unroll
            for (int p = 0; p < 4; p++) {
                int r = rs + 32 * p;
                const float* ap = xs + (size_t)(n0 + r) * (Tt * Dd);
                s8v vh, vl;
                #pragma unroll
                for (int i = 0; i < 8; i++) {
                    ushort hi_, lo_; split2(ap[i], hi_, lo_);
                    vh[i] = (short)hi_; vl[i] = (short)lo_;
                }
                *(s8v*)&Ah[r * 72 + cs] = vh;
                *(s8v*)&Al[r * 72 + cs] = vl;
            }
        } else {
            int ko = kb - Dd;
            #pragma unroll
            for (int p = 0; p < 4; p++) {
                int r = rs + 32 * p;
                size_t o = (size_t)(n0 + r) * Hh + ko + cs;
                *(s8v*)&Ah[r * 72 + cs] = *(const s8v*)&hhi[o];
                *(s8v*)&Al[r * 72 + cs] = *(const s8v*)&hlo[o];
            }
        }
        #pragma unroll
        for (int p = 0; p < 2; p++) {
            int r = rs + 32 * p;
            size_t o = (size_t)(j0 + r) * KK + kb + cs;
            *(s8v*)&Bh[r * 72 + cs] = *(const s8v*)&Whi[o];
            *(s8v*)&Bl[r * 72 + cs] = *(const s8v*)&Wlo[o];
        }
        __syncthreads();
        #pragma unroll
        for (int ks = 0; ks < 2; ks++) {
            s8v ah0 = *(const s8v*)&Ah[(wave * 32 + l15) * 72 + ks * 32 + quad * 8];
            s8v ah1 = *(const s8v*)&Ah[(wave * 32 + 16 + l15) * 72 + ks * 32 + quad * 8];
            s8v al0 = *(const s8v*)&Al[(wave * 32 + l15) * 72 + ks * 32 + quad * 8];
            s8v al1 = *(const s8v*)&Al[(wave * 32 + 16 + l15) * 72 + ks * 32 + quad * 8];
            #pragma unroll
            for (int ct = 0; ct < 4; ct++) {
                s8v bh = *(const s8v*)&Bh[(ct * 16 + l15) * 72 + ks * 32 + quad * 8];
                s8v bl = *(const s8v*)&Bl[(ct * 16 + l15) * 72 + ks * 32 + quad * 8];
                acc[0][ct] = __builtin_amdgcn_mfma_f32_16x16x32_bf16(ah0, bh, acc[0][ct], 0, 0, 0);
                acc[0][ct] = __builtin_amdgcn_mfma_f32_16x16x32_bf16(ah0, bl, acc[0][ct], 0, 0, 0);
                acc[0][ct] = __builtin_amdgcn_mfma_f32_16x16x32_bf16(al0, bh, acc[0][ct], 0, 0, 0);
                acc[1][ct] = __builtin_amdgcn_mfma_f32_16x16x32_bf16(ah1, bh, acc[1][ct], 0, 0, 0);
                acc[1][ct] = __builtin_amdgcn_mfma_f32_16x16x32_bf16(ah1, bl, acc[1][ct], 0, 0, 0);
                acc[1][ct] = __builtin_amdgcn_mfma_f32_16x16x32_bf16(al1, bh, acc[1][ct], 0, 0, 0);
            }
        }
    }
    #pragma unroll
    for (int rt = 0; rt < 2; rt++) {
        #pragma unroll
        for (int ct = 0; ct < 4; ct++) {
            int j = j0 + ct * 16 + l15;
            #pragma unroll
            for (int rr = 0; rr < 4; rr++) {
                int row = n0 + wave * 32 + rt * 16 + quad * 4 + rr;
                gout[(size_t)row * G4 + j] = acc[rt][ct][rr];
            }
        }
    }
}

// ---------------------------------------------------------------------------
// Per step: fused LSTM pointwise + attn weighted-sum (fp16 AW) + next-step
// softmax weights. One block per n; thread handles 4 consecutive j.
// gates = g0+g1+g2+g3 + bias + sum_l w[l]*AW[n][l][:]
// ---------------------------------------------------------------------------
__global__ __launch_bounds__(256) void lstm_fused(
    const float* __restrict__ g0, const float* __restrict__ g1,
    const float* __restrict__ g2, const float* __restrict__ g3,
    const float* __restrict__ bias, const f16* __restrict__ AW,
    float* __restrict__ wbuf, const float* __restrict__ A,
    float* __restrict__ c, ushort* __restrict__ hhi, ushort* __restrict__ hlo,
    float* __restrict__ out, int t)
{
    int n = blockIdx.x;
    int tid = threadIdx.x;
    int lane = tid & 63, wave = tid >> 6;
    int j4 = tid * 4;
    __shared__ float wsh[16];
    __shared__ float red[4][16];
    if (tid < 16) wsh[tid] = wbuf[n * 16 + tid];
    __syncthreads();
    float w[16];
    #pragma unroll
    for (int l = 0; l < 16; l++) w[l] = wsh[l];

    f4v acc[4];
    #pragma unroll
    for (int q = 0; q < 4; q++) acc[q] = (f4v){0.f, 0.f, 0.f, 0.f};
    const f16* awp = AW + (size_t)n * 16 * G4;
    #pragma unroll
    for (int l = 0; l < 16; l++) {
        float wl = w[l];
        #pragma unroll
        for (int q = 0; q < 4; q++) {
            h4v v = *(const h4v*)&awp[(size_t)l * G4 + q * Hh + j4];
            acc[q][0] += wl * (float)v[0]; acc[q][1] += wl * (float)v[1];
            acc[q][2] += wl * (float)v[2]; acc[q][3] += wl * (float)v[3];
        }
    }

    size_t base = (size_t)n * G4;
    f4v gv[4];
    #pragma unroll
    for (int q = 0; q < 4; q++) {
        f4v a0 = *(const f4v*)&g0[base + q * Hh + j4];
        f4v a1 = *(const f4v*)&g1[base + q * Hh + j4];
        f4v a2 = *(const f4v*)&g2[base + q * Hh + j4];
        f4v a3 = *(const f4v*)&g3[base + q * Hh + j4];
        f4v bv = *(const f4v*)&bias[q * Hh + j4];
        #pragma unroll
        for (int e = 0; e < 4; e++)
            gv[q][e] = (a0[e] + a1[e]) + (a2[e] + a3[e]) + bv[e] + acc[q][e];
    }
    int i4 = n * Hh + j4;
    f4v cold = *(const f4v*)&c[i4];
    f4v cnew, hnew;
    #pragma unroll
    for (int e = 0; e < 4; e++) {
        float si = 1.f / (1.f + expf(-gv[0][e]));
        float sf = 1.f / (1.f + expf(-gv[1][e]));
        float so = 1.f / (1.f + expf(-gv[2][e]));
        float tg = tanhf(gv[3][e]);
        float cn = sf * cold[e] + si * tg;
        float hn = so * tanhf(cn);
        cnew[e] = cn; hnew[e] = hn;
    }
    *(f4v*)&c[i4] = cnew;
    s4v vh, vl;
    #pragma unroll
    for (int e = 0; e < 4; e++) {
        ushort hi, lo; split2(hnew[e], hi, lo);
        vh[e] = (short)hi; vl[e] = (short)lo;
    }
    *(s4v*)&hhi[i4] = vh;
    *(s4v*)&hlo[i4] = vl;
    *(f4v*)&out[((size_t)n * Tt + t) * Hh + j4] = hnew;

    // next-step attention weights from hnew
    float part[16];
    #pragma unroll
    for (int l = 0; l < 16; l++) part[l] = 0.f;
    #pragma unroll
    for (int r = 0; r < 4; r++) {
        float hv = hnew[r];
        const f4v* ap = (const f4v*)(A + ((size_t)n * Hh + j4 + r) * 16);
        #pragma unroll
        for (int q = 0; q < 4; q++) {
            f4v v = ap[q];
            part[q * 4 + 0] += v[0] * hv; part[q * 4 + 1] += v[1] * hv;
            part[q * 4 + 2] += v[2] * hv; part[q * 4 + 3] += v[3] * hv;
        }
    }
    #pragma unroll
    for (int l = 0; l < 16; l++) {
        float v = part[l];
        #pragma unroll
        for (int off = 32; off > 0; off >>= 1) v += __shfl_down(v, off);
        if (lane == 0) red[wave][l] = v;
    }
    __syncthreads();
    if (tid == 0) {
        float sc[16]; float mx = -3.4e38f;
        #pragma unroll
        for (int l = 0; l < 16; l++) {
            sc[l] = (red[0][l] + red[1][l] + red[2][l] + red[3][l]) * 0.03125f;
            mx = fmaxf(mx, sc[l]);
        }
        float sum = 0.f;
        #pragma unroll
        for (int l = 0; l < 16; l++) { sc[l] = expf(sc[l] - mx); sum += sc[l]; }
        float inv = 1.f / sum;
        #pragma unroll
        for (int l = 0; l < 16; l++) wbuf[n * 16 + l] = sc[l] * inv;
    }
}

// ---------------------------------------------------------------------------
extern "C" void kernel_launch(void* const* d_in, const int* in_sizes, int n_in,
                              void* d_out, int out_size, void* d_ws, size_t ws_size,
                              hipStream_t stream)
{
    const float* x  = (const float*)d_in[0];
    const float* A  = (const float*)d_in[1];
    const float* Wx = (const float*)d_in[2];
    const float* Wh = (const float*)d_in[3];
    const float* Wa = (const float*)d_in[4];
    const float* b  = (const float*)d_in[5];
    float* out = (float*)d_out;

    // workspace layout (~112 MB)
    char* p = (char*)d_ws;
    ushort* Whi  = (ushort*)p;  p += (size_t)G4 * KK * 2;        // 20.97 MB
    ushort* Wlo  = (ushort*)p;  p += (size_t)G4 * KK * 2;        // 20.97 MB
    float*  h    = (float*)p;   p += (size_t)Nn * Hh * 4;        // 1 MB
    float*  c    = (float*)p;   p += (size_t)Nn * Hh * 4;        // 1 MB
    float*  g0   = (float*)p;   p += (size_t)Nn * G4 * 4;        // 4 MB
    float*  g1   = (float*)p;   p += (size_t)Nn * G4 * 4;        // 4 MB
    float*  g2   = (float*)p;   p += (size_t)Nn * G4 * 4;        // 4 MB
    float*  g3   = (float*)p;   p += (size_t)Nn * G4 * 4;        // 4 MB
    ushort* hhi  = (ushort*)p;  p += (size_t)Nn * Hh * 2;        // 0.5 MB
    ushort* hlo  = (ushort*)p;  p += (size_t)Nn * Hh * 2;        // 0.5 MB
    ushort* Athi = (ushort*)p;  p += (size_t)Nn * 16 * Hh * 2;   // 8.39 MB
    ushort* Atlo = (ushort*)p;  p += (size_t)Nn * 16 * Hh * 2;   // 8.39 MB
    f16*    AW   = (f16*)p;     p += (size_t)Nn * 16 * G4 * 2;   // 33.55 MB
    float*  wbuf = (float*)p;   p += (size_t)Nn * 16 * 4;        // 16 KB

    prep_W<<<dim3(KK / 64, G4 / 64), 256, 0, stream>>>(Wx, Wh, Wa, Whi, Wlo);
    prep_A<<<Nn, 256, 0, stream>>>(A, Athi, Atlo);
    aw_gemm<<<dim3(G4 / 64, (Nn * 16) / 64), 256, 0, stream>>>(
        Athi, Atlo, Whi, Wlo, AW);
    init_h0<<<(Nn * Hh) / 256, 256, 0, stream>>>(A, h, c, hhi, hlo);
    calc_w<<<Nn, 256, 0, stream>>>(A, h, wbuf);
    for (int t = 0; t < Tt; t++) {
        gemm_step<<<dim3(G4 / 64, Nn / 128, 4), 256, 0, stream>>>(
            x, hhi, hlo, Whi, Wlo, g0, g1, g2, g3, t);
        lstm_fused<<<Nn, 256, 0, stream>>>(
            g0, g1, g2, g3, b, AW, wbuf, A, c, hhi, hlo, out, t);
    }
}